// Round 4
// baseline (420.001 us; speedup 1.0000x reference)
//
#include <hip/hip_runtime.h>
#include <hip/hip_fp16.h>

// LightGCN propagation on MI355X — round 7: build-phase consolidation.
// N = 100000 nodes, D = 128, E = 2,000,000 edges, 3 layers.
//
// Round-6 post-mortem: spmm = 86.2 us each; 4x wider gathers bought only
// +10% -> random-line L3 miss path (~3.3-3.9 TB/s) is the spmm wall, and
// FETCH 279 MB is ~25% above the 8-XCD replication floor (221 MB). spmm is
// left UNTOUCHED this round. Remaining: 418 - 259 = 159 us of build, vs
// ~80 us of traffic-justified work -> serialization (13 dispatches, small
// kernels). Round 7:
//   - lgcn_prep: conv + per-block edge histogram + scan-status zero fused
//     in one kernel (role by blockIdx range); conv's 77 MB streaming hides
//     under phist's LDS-atomic phase.
//   - lgcn_scan: single decoupled-lookback scan over the 131072-entry
//     ghist (128 tiles, all co-resident on 256 CUs -> spin is safe);
//     replaces scan1+scan2+scan3.
//   - lgcn_place: single-pass — bucket edges cached in LDS (cap 7168,
//     global-re-read fallback), hist+scan+scatter without re-reading
//     staging from global.
// Dispatches: 13 -> 7.
//
// ws layout (256 B aligned):
//   bufA : nd fp16 (x0, later x2)                 25.6 MB
//   bufB : nd fp16 (x1; int2 staging during build) 25.6 MB
//   edges: E int2                                  16 MB
//   row_ptr(n+1), ghist(512*256), gbase(+1), tstat ~1.5 MB

#define DIM  128
#define PB   256   // partition blocks
#define KPAD 512   // padded bucket count (nbuck = ceil(n/256) = 391 <= 512)
#define RPB  256   // rows per bucket
#define NSCAN (KPAD * PB)     // 131072
#define NTILES (NSCAN / 1024) // 128 scan tiles
#define PCAP 7168             // place LDS edge cache (56 KB); avg bucket 5120

static inline size_t align_up(size_t v, size_t a) { return (v + a - 1) & ~(a - 1); }

// Fused: conv (emb->fp16 x0), per-block coarse histogram, scan-status zero.
__global__ void __launch_bounds__(256)
lgcn_prep(const float2* __restrict__ emb, __half2* __restrict__ x0, int n2,
          const int* __restrict__ rows, int* __restrict__ ghist, int nedges,
          unsigned long long* __restrict__ tstat) {
    __shared__ int h[KPAD];
    const int b = blockIdx.x, tid = threadIdx.x;
    if (b < PB) {
        // histogram role: block b owns edges [b*chunk, (b+1)*chunk)
        for (int k = tid; k < KPAD; k += 256) h[k] = 0;
        __syncthreads();
        const int chunk = (nedges + PB - 1) / PB;
        const int beg = b * chunk;
        const int end = min(beg + chunk, nedges);
        for (int e = beg + tid; e < end; e += 256)
            atomicAdd(&h[rows[e] >> 8], 1);
        __syncthreads();
        for (int k = tid; k < KPAD; k += 256) ghist[(k << 8) + b] = h[k];
    } else if (b == PB) {
        if (tid < NTILES) tstat[tid] = 0ull;
    } else {
        const int i = (b - PB - 1) * 256 + tid;
        if (i < n2) x0[i] = __float22half2_rn(emb[i]);
    }
}

// Single-kernel decoupled-lookback exclusive scan of ghist -> gbase.
// 128 tiles of 1024; all tiles co-resident (<= 256 CUs) so spinning on the
// predecessor is deadlock-free. tstat[t] packs {value:32 | flag:32},
// flag 0=empty 1=aggregate 2=inclusive.
__global__ void __launch_bounds__(256)
lgcn_scan(const int* __restrict__ ghist, int* __restrict__ gbase,
          unsigned long long* __restrict__ tstat, int nscan) {
    __shared__ int wsum[4];
    __shared__ int btot_s, prev_s;
    const int tile = blockIdx.x;
    const int tid  = threadIdx.x;
    const int lane = tid & 63;
    const int wid  = tid >> 6;
    const int i0   = tile * 1024 + tid * 4;

    int4 c = *(const int4*)(ghist + i0);
    const int t1 = c.x + c.y, t2 = t1 + c.z, tsum = t2 + c.w;

    int incl = tsum;
    #pragma unroll
    for (int off = 1; off < 64; off <<= 1) {
        int t = __shfl_up(incl, off, 64);
        if (lane >= off) incl += t;
    }
    if (lane == 63) wsum[wid] = incl;
    __syncthreads();
    int woff = 0;
    #pragma unroll
    for (int w = 0; w < 4; ++w) woff += (w < wid) ? wsum[w] : 0;
    const int ex = woff + incl - tsum;
    if (tid == 255) btot_s = woff + incl;
    __syncthreads();
    const int btot = btot_s;

    if (tid == 0) {
        if (tile == 0) {
            __hip_atomic_store(&tstat[0],
                (((unsigned long long)(unsigned)btot) << 32) | 2ull,
                __ATOMIC_RELEASE, __HIP_MEMORY_SCOPE_AGENT);
            prev_s = 0;
        } else {
            __hip_atomic_store(&tstat[tile],
                (((unsigned long long)(unsigned)btot) << 32) | 1ull,
                __ATOMIC_RELEASE, __HIP_MEMORY_SCOPE_AGENT);
            int t = tile - 1, run = 0;
            while (true) {
                unsigned long long st = __hip_atomic_load(&tstat[t],
                    __ATOMIC_ACQUIRE, __HIP_MEMORY_SCOPE_AGENT);
                unsigned f = (unsigned)st & 3u;
                if (f == 0u) { __builtin_amdgcn_s_sleep(1); continue; }
                run += (int)(unsigned)(st >> 32);
                if (f == 2u) break;
                --t;
            }
            __hip_atomic_store(&tstat[tile],
                (((unsigned long long)(unsigned)(run + btot)) << 32) | 2ull,
                __ATOMIC_RELEASE, __HIP_MEMORY_SCOPE_AGENT);
            prev_s = run;
        }
    }
    __syncthreads();
    const int pv = prev_s;

    int4 o;
    o.x = pv + ex;
    o.y = pv + ex + c.x;
    o.z = pv + ex + t1;
    o.w = pv + ex + t2;
    *(int4*)(gbase + i0) = o;
    if (tile == gridDim.x - 1 && tid == 255) gbase[nscan] = pv + btot;
}

// Deterministic partition: block b re-reads its chunk; LDS counters start at
// gbase[k][b]; each edge goes to a contiguous (block,bucket) range written by
// this CU only.
__global__ void __launch_bounds__(256)
lgcn_part(const int* __restrict__ rows, const int* __restrict__ cols,
          const float* __restrict__ vals, const int* __restrict__ gbase,
          int2* __restrict__ staging, int nedges) {
    __shared__ int lcnt[KPAD];
    const int b = blockIdx.x, tid = threadIdx.x;
    for (int k = tid; k < KPAD; k += 256) lcnt[k] = gbase[(k << 8) + b];
    __syncthreads();
    const int chunk = (nedges + PB - 1) / PB;
    const int beg = b * chunk;
    const int end = min(beg + chunk, nedges);
    for (int e = beg + tid; e < end; e += 256) {
        int r   = rows[e];
        int pos = atomicAdd(&lcnt[r >> 8], 1);
        staging[pos] = make_int2(cols[e] | ((r & 255) << 17), __float_as_int(vals[e]));
    }
}

// One block per 256-row bucket, single pass over staging: edges cached in
// LDS (cap PCAP, fallback re-reads global), LDS row-hist + block scan ->
// row_ptr + cursors, scatter to exact CSR slots (single-XCD ~40 KB window).
__global__ void __launch_bounds__(256)
lgcn_place(const int* __restrict__ gbase, const int2* __restrict__ staging,
           int* __restrict__ row_ptr, int2* __restrict__ edges, int n, int nbuck) {
    __shared__ int rcnt[RPB];
    __shared__ int cur[RPB];
    __shared__ int wsum[4];
    __shared__ int2 cache[PCAP];
    const int k    = blockIdx.x;
    const int tid  = threadIdx.x;
    const int lane = tid & 63;
    const int wid  = tid >> 6;
    const int base = gbase[k << 8];          // gbase[k][0]
    const int next = gbase[(k + 1) << 8];    // gbase[k+1][0]
    const int cnt  = next - base;
    const bool fit = (cnt <= PCAP);

    rcnt[tid] = 0;
    __syncthreads();
    if (fit) {
        for (int i = tid; i < cnt; i += 256) {
            int2 p = staging[base + i];
            cache[i] = p;
            atomicAdd(&rcnt[(p.x >> 17) & 255], 1);
        }
    } else {
        for (int i = base + tid; i < next; i += 256)
            atomicAdd(&rcnt[(staging[i].x >> 17) & 255], 1);
    }
    __syncthreads();

    // block-exclusive scan of the 256 row counts
    const int v = rcnt[tid];
    int incl = v;
    #pragma unroll
    for (int off = 1; off < 64; off <<= 1) {
        int t = __shfl_up(incl, off, 64);
        if (lane >= off) incl += t;
    }
    if (lane == 63) wsum[wid] = incl;
    __syncthreads();
    int woff = 0;
    #pragma unroll
    for (int w = 0; w < 4; ++w) woff += (w < wid) ? wsum[w] : 0;
    const int ex = woff + incl - v;

    cur[tid] = base + ex;
    const int r = (k << 8) + tid;
    if (r < n) row_ptr[r] = base + ex;
    if (k == nbuck - 1 && tid == 0) row_ptr[n] = next;
    __syncthreads();

    if (fit) {
        for (int i = tid; i < cnt; i += 256) {
            int2 p  = cache[i];
            int pos = atomicAdd(&cur[(p.x >> 17) & 255], 1);
            edges[pos] = make_int2(p.x & 0x1FFFF, p.y);
        }
    } else {
        for (int i = base + tid; i < next; i += 256) {
            int2 p  = staging[i];
            int pos = atomicAdd(&cur[(p.x >> 17) & 255], 1);
            edges[pos] = make_int2(p.x & 0x1FFFF, p.y);
        }
    }
}

// Wide-gather SpMM (unchanged from round 6). One wave per row. lane = 16*g + l:
//   g = lane>>4 : edge slot (4 edges per gather instruction)
//   l = lane&15 : dim quarter, dims [8l, 8l+8) as one int4 of 8 fp16.
// mode 0: xout[row] = fp16(s)
// mode 1: out[row]  = (emb[row] + x1[row] + x2[row] + s) * 0.25  (fp32)
__global__ void __launch_bounds__(256)
lgcn_spmm(const int* __restrict__ row_ptr, const int2* __restrict__ edges,
          const __half2* __restrict__ xin, __half2* __restrict__ xout,
          const float2* __restrict__ emb, const __half2* __restrict__ x1h,
          float2* __restrict__ out, int n, int mode) {
    const int wave = blockIdx.x * 4 + (threadIdx.x >> 6);
    const int lane = threadIdx.x & 63;
    const int g    = lane >> 4;
    const int l    = lane & 15;
    if (wave >= n) return;
    const int beg = row_ptr[wave];
    const int end = row_ptr[wave + 1];

    const int4* __restrict__ x4 = (const int4*)xin;  // 16 int4 per row

    float a0 = 0.f, a1 = 0.f, a2 = 0.f, a3 = 0.f;
    float a4 = 0.f, a5 = 0.f, a6 = 0.f, a7 = 0.f;

#define FMA8(Q, V)                                                        \
    {                                                                     \
        float2 f0 = __half22float2(*(const __half2*)&(Q).x);              \
        float2 f1 = __half22float2(*(const __half2*)&(Q).y);              \
        float2 f2 = __half22float2(*(const __half2*)&(Q).z);              \
        float2 f3 = __half22float2(*(const __half2*)&(Q).w);              \
        a0 = fmaf((V), f0.x, a0); a1 = fmaf((V), f0.y, a1);               \
        a2 = fmaf((V), f1.x, a2); a3 = fmaf((V), f1.y, a3);               \
        a4 = fmaf((V), f2.x, a4); a5 = fmaf((V), f2.y, a5);               \
        a6 = fmaf((V), f3.x, a6); a7 = fmaf((V), f3.y, a7);               \
    }

    int e = beg;
    // main: 16 edges per iteration = 4 independent wide gathers (64 lines).
    for (; e + 16 <= end; e += 16) {
        int2 d0 = edges[e + g];
        int2 d1 = edges[e + 4 + g];
        int2 d2 = edges[e + 8 + g];
        int2 d3 = edges[e + 12 + g];
        int4 q0 = x4[d0.x * 16 + l];
        int4 q1 = x4[d1.x * 16 + l];
        int4 q2 = x4[d2.x * 16 + l];
        int4 q3 = x4[d3.x * 16 + l];
        FMA8(q0, __int_as_float(d0.y));
        FMA8(q1, __int_as_float(d1.y));
        FMA8(q2, __int_as_float(d2.y));
        FMA8(q3, __int_as_float(d3.y));
    }
    // mid tail: 8 edges.
    for (; e + 8 <= end; e += 8) {
        int2 d0 = edges[e + g];
        int2 d1 = edges[e + 4 + g];
        int4 q0 = x4[d0.x * 16 + l];
        int4 q1 = x4[d1.x * 16 + l];
        FMA8(q0, __int_as_float(d0.y));
        FMA8(q1, __int_as_float(d1.y));
    }
    // masked tail: up to 4 edges per iteration; masked lanes gather row 0
    // (hot line) with v = 0 -> no contribution.
    for (; e < end; e += 4) {
        const int ee = e + g;
        int2 d = (ee < end) ? edges[ee] : make_int2(0, 0);
        int4 q = x4[d.x * 16 + l];
        FMA8(q, __int_as_float(d.y));
    }
#undef FMA8

    // reduce across the 4 edge slots (groups differ in lane bits 4,5)
    a0 += __shfl_xor(a0, 16); a0 += __shfl_xor(a0, 32);
    a1 += __shfl_xor(a1, 16); a1 += __shfl_xor(a1, 32);
    a2 += __shfl_xor(a2, 16); a2 += __shfl_xor(a2, 32);
    a3 += __shfl_xor(a3, 16); a3 += __shfl_xor(a3, 32);
    a4 += __shfl_xor(a4, 16); a4 += __shfl_xor(a4, 32);
    a5 += __shfl_xor(a5, 16); a5 += __shfl_xor(a5, 32);
    a6 += __shfl_xor(a6, 16); a6 += __shfl_xor(a6, 32);
    a7 += __shfl_xor(a7, 16); a7 += __shfl_xor(a7, 32);

    if (mode == 0) {
        if (g == 0) {
            int4 r;
            __half2 h0 = __float22half2_rn(make_float2(a0, a1));
            __half2 h1 = __float22half2_rn(make_float2(a2, a3));
            __half2 h2 = __float22half2_rn(make_float2(a4, a5));
            __half2 h3 = __float22half2_rn(make_float2(a6, a7));
            r.x = *(const int*)&h0; r.y = *(const int*)&h1;
            r.z = *(const int*)&h2; r.w = *(const int*)&h3;
            ((int4*)xout)[wave * 16 + l] = r;
        }
    } else {
        float4 e0 = ((const float4*)emb)[wave * 32 + l * 2 + 0];
        float4 e1 = ((const float4*)emb)[wave * 32 + l * 2 + 1];
        int4  h1q = ((const int4*)x1h)[wave * 16 + l];
        int4  h2q = ((const int4*)xin)[wave * 16 + l];
        float2 b0 = __half22float2(*(const __half2*)&h1q.x);
        float2 b1 = __half22float2(*(const __half2*)&h1q.y);
        float2 b2 = __half22float2(*(const __half2*)&h1q.z);
        float2 b3 = __half22float2(*(const __half2*)&h1q.w);
        float2 c0 = __half22float2(*(const __half2*)&h2q.x);
        float2 c1 = __half22float2(*(const __half2*)&h2q.y);
        float2 c2 = __half22float2(*(const __half2*)&h2q.z);
        float2 c3 = __half22float2(*(const __half2*)&h2q.w);
        if (g == 0) {
            float4 r0, r1;
            r0.x = (e0.x + b0.x + c0.x + a0) * 0.25f;
            r0.y = (e0.y + b0.y + c0.y + a1) * 0.25f;
            r0.z = (e0.z + b1.x + c1.x + a2) * 0.25f;
            r0.w = (e0.w + b1.y + c1.y + a3) * 0.25f;
            r1.x = (e1.x + b2.x + c2.x + a4) * 0.25f;
            r1.y = (e1.y + b2.y + c2.y + a5) * 0.25f;
            r1.z = (e1.z + b3.x + c3.x + a6) * 0.25f;
            r1.w = (e1.w + b3.y + c3.y + a7) * 0.25f;
            ((float4*)out)[wave * 32 + l * 2 + 0] = r0;
            ((float4*)out)[wave * 32 + l * 2 + 1] = r1;
        }
    }
}

extern "C" void kernel_launch(void* const* d_in, const int* in_sizes, int n_in,
                              void* d_out, int out_size, void* d_ws, size_t ws_size,
                              hipStream_t stream) {
    const float* emb  = (const float*)d_in[0];
    const int*   rows = (const int*)d_in[1];
    const int*   cols = (const int*)d_in[2];
    const float* vals = (const float*)d_in[3];

    const int  n_nodes = in_sizes[0] / DIM;    // 100000
    const int  nedges  = in_sizes[1];          // 2000000
    const long nd      = (long)n_nodes * DIM;  // 12.8M

    char* ws = (char*)d_ws;
    size_t off = 0;
    __half2* bufA = (__half2*)(ws + off); off = align_up(off + nd * 2, 256);   // x0 then x2
    __half2* bufB = (__half2*)(ws + off); off = align_up(off + nd * 2, 256);   // x1 / staging
    int2* edges   = (int2*)(ws + off);    off = align_up(off + (size_t)nedges * 8, 256);
    int* row_ptr  = (int*)(ws + off);     off = align_up(off + (size_t)(n_nodes + 1) * 4, 256);
    int* ghist    = (int*)(ws + off);     off = align_up(off + (size_t)NSCAN * 4, 256);
    int* gbase    = (int*)(ws + off);     off = align_up(off + ((size_t)NSCAN + 1) * 4, 256);
    unsigned long long* tstat = (unsigned long long*)(ws + off);
    off = align_up(off + (size_t)NTILES * 8, 256);
    float2* out   = (float2*)d_out;

    int2* staging = (int2*)bufB;  // bufB is dead until spmm layer 1

    const int BS = 256;
    const int n2      = (int)(nd / 2);
    const int grid_c  = (n2 + BS - 1) / BS;               // 25000 conv blocks
    const int nbuck   = (n_nodes + RPB - 1) / RPB;        // 391 (<= KPAD)
    const int grid_s  = (n_nodes + 3) / 4;                // 4 rows per block

    // conv + histogram + scan-status zero (one kernel)
    lgcn_prep<<<PB + 1 + grid_c, BS, 0, stream>>>((const float2*)emb, bufA, n2,
                                                  rows, ghist, nedges, tstat);
    // single-kernel decoupled-lookback scan
    lgcn_scan<<<NTILES, BS, 0, stream>>>(ghist, gbase, tstat, NSCAN);
    // deterministic partition + single-pass place
    lgcn_part<<<PB, BS, 0, stream>>>(rows, cols, vals, gbase, staging, nedges);
    lgcn_place<<<nbuck, BS, 0, stream>>>(gbase, staging, row_ptr, edges, n_nodes, nbuck);

    // 3 SpMM layers: x1 = A x0, x2 = A x1, out = (emb + x1 + x2 + A x2)/4
    lgcn_spmm<<<grid_s, BS, 0, stream>>>(row_ptr, edges, bufA, bufB,
                                         nullptr, nullptr, nullptr, n_nodes, 0);
    lgcn_spmm<<<grid_s, BS, 0, stream>>>(row_ptr, edges, bufB, bufA,
                                         nullptr, nullptr, nullptr, n_nodes, 0);
    lgcn_spmm<<<grid_s, BS, 0, stream>>>(row_ptr, edges, bufA, nullptr,
                                         (const float2*)emb, bufB, out, n_nodes, 1);
}

// Round 6
// 409.319 us; speedup vs baseline: 1.0261x; 1.0261x over previous
//
#include <hip/hip_runtime.h>
#include <hip/hip_fp16.h>

// LightGCN propagation on MI355X — round 9: fixed wave-parallel scan lookback.
// N = 100000 nodes, D = 128, E = 2,000,000 edges, 3 layers.
//
// Round-8 post-mortem: container failed twice; audit found a genuine bug in
// the wave-parallel lookback — a window with NO inclusive entry (inc_mask==0,
// l_star=-1) dropped all 64 aggregates (contrib = lane<=-1 -> 0) instead of
// summing them, producing timing-dependent wrong gbase. Fixed here:
//   inc_mask==0  -> contrib = v for ALL lanes, continue to next window;
//   inc_mask!=0  -> contrib = v for lanes <= l_star (nearest inclusive), stop.
// prep / part / place / spmm byte-identical to round 7/8 for isolation.
//
// ws layout (256 B aligned):
//   bufA : nd fp16 (x0, later x2)                 25.6 MB
//   bufB : nd fp16 (x1; int2 staging during build) 25.6 MB
//   edges: E int2                                  16 MB
//   row_ptr(n+1), ghist(512*256), gbase(+1), tstat ~1.5 MB

#define DIM  128
#define PB   256   // partition blocks
#define KPAD 512   // padded bucket count (nbuck = ceil(n/256) = 391 <= 512)
#define RPB  256   // rows per bucket
#define NSCAN (KPAD * PB)     // 131072
#define NTILES (NSCAN / 1024) // 128 scan tiles
#define PCAP 7168             // place LDS edge cache (56 KB); avg bucket 5120

static inline size_t align_up(size_t v, size_t a) { return (v + a - 1) & ~(a - 1); }

// Fused: conv (emb->fp16 x0), per-block coarse histogram, scan-status zero.
__global__ void __launch_bounds__(256)
lgcn_prep(const float2* __restrict__ emb, __half2* __restrict__ x0, int n2,
          const int* __restrict__ rows, int* __restrict__ ghist, int nedges,
          unsigned long long* __restrict__ tstat) {
    __shared__ int h[KPAD];
    const int b = blockIdx.x, tid = threadIdx.x;
    if (b < PB) {
        // histogram role: block b owns edges [b*chunk, (b+1)*chunk)
        for (int k = tid; k < KPAD; k += 256) h[k] = 0;
        __syncthreads();
        const int chunk = (nedges + PB - 1) / PB;
        const int beg = b * chunk;
        const int end = min(beg + chunk, nedges);
        for (int e = beg + tid; e < end; e += 256)
            atomicAdd(&h[rows[e] >> 8], 1);
        __syncthreads();
        for (int k = tid; k < KPAD; k += 256) ghist[(k << 8) + b] = h[k];
    } else if (b == PB) {
        if (tid < NTILES) tstat[tid] = 0ull;
    } else {
        const int i = (b - PB - 1) * 256 + tid;
        if (i < n2) x0[i] = __float22half2_rn(emb[i]);
    }
}

// Single-kernel decoupled-lookback exclusive scan of ghist -> gbase.
// 128 tiles of 1024; all tiles co-resident (<= 256 CUs) so spinning on
// predecessors is deadlock-free. tstat[t] packs {value:32 | flag:32},
// flag 0=empty 1=aggregate 2=inclusive. Lookback is WAVE-PARALLEL:
// lane l inspects predecessor tile-1-l (window of 64). If the window has an
// inclusive entry: sum lanes <= nearest-inclusive and stop. If not: sum all
// 64 aggregates and continue to the next window.
__global__ void __launch_bounds__(256)
lgcn_scan(const int* __restrict__ ghist, int* __restrict__ gbase,
          unsigned long long* __restrict__ tstat, int nscan) {
    __shared__ int wsum[4];
    __shared__ int btot_s, prev_s;
    const int tile = blockIdx.x;
    const int tid  = threadIdx.x;
    const int lane = tid & 63;
    const int wid  = tid >> 6;
    const int i0   = tile * 1024 + tid * 4;

    int4 c = *(const int4*)(ghist + i0);
    const int t1 = c.x + c.y, t2 = t1 + c.z, tsum = t2 + c.w;

    int incl = tsum;
    #pragma unroll
    for (int off = 1; off < 64; off <<= 1) {
        int t = __shfl_up(incl, off, 64);
        if (lane >= off) incl += t;
    }
    if (lane == 63) wsum[wid] = incl;
    __syncthreads();
    int woff = 0;
    #pragma unroll
    for (int w = 0; w < 4; ++w) woff += (w < wid) ? wsum[w] : 0;
    const int ex = woff + incl - tsum;
    if (tid == 255) btot_s = woff + incl;
    __syncthreads();
    const int btot = btot_s;

    if (tile == 0) {
        if (tid == 0) {
            __hip_atomic_store(&tstat[0],
                (((unsigned long long)(unsigned)btot) << 32) | 2ull,
                __ATOMIC_RELEASE, __HIP_MEMORY_SCOPE_AGENT);
            prev_s = 0;
        }
    } else if (wid == 0) {
        if (lane == 0)
            __hip_atomic_store(&tstat[tile],
                (((unsigned long long)(unsigned)btot) << 32) | 1ull,
                __ATOMIC_RELEASE, __HIP_MEMORY_SCOPE_AGENT);
        int run = 0;
        int base_p = tile - 1;   // nearest predecessor handled by lane 0
        while (true) {
            const int p = base_p - lane;
            unsigned long long st;
            if (p >= 0) {
                do {
                    st = __hip_atomic_load(&tstat[p],
                        __ATOMIC_ACQUIRE, __HIP_MEMORY_SCOPE_AGENT);
                    if (((unsigned)st & 3u) != 0u) break;
                    __builtin_amdgcn_s_sleep(1);
                } while (true);
            } else {
                st = 2ull;  // virtual tile: value 0, inclusive
            }
            const unsigned f = (unsigned)st & 3u;
            const int v = (int)(unsigned)(st >> 32);
            const unsigned long long inc_mask = __ballot(f == 2u);
            int contrib;
            if (inc_mask != 0ull) {
                const int l_star = (int)(__ffsll((long long)inc_mask) - 1);
                contrib = (lane <= l_star) ? v : 0;   // aggregates before + the inclusive
            } else {
                contrib = v;                          // whole window is aggregates
            }
            #pragma unroll
            for (int off = 1; off < 64; off <<= 1)
                contrib += __shfl_xor(contrib, off);
            run += contrib;
            if (inc_mask != 0ull) break;
            base_p -= 64;
        }
        if (lane == 0) {
            __hip_atomic_store(&tstat[tile],
                (((unsigned long long)(unsigned)(run + btot)) << 32) | 2ull,
                __ATOMIC_RELEASE, __HIP_MEMORY_SCOPE_AGENT);
            prev_s = run;
        }
    }
    __syncthreads();
    const int pv = prev_s;

    int4 o;
    o.x = pv + ex;
    o.y = pv + ex + c.x;
    o.z = pv + ex + t1;
    o.w = pv + ex + t2;
    *(int4*)(gbase + i0) = o;
    if (tile == gridDim.x - 1 && tid == 255) gbase[nscan] = pv + btot;
}

// Deterministic partition: block b re-reads its chunk; LDS counters start at
// gbase[k][b]; each edge goes to a contiguous (block,bucket) range written by
// this CU only.
__global__ void __launch_bounds__(256)
lgcn_part(const int* __restrict__ rows, const int* __restrict__ cols,
          const float* __restrict__ vals, const int* __restrict__ gbase,
          int2* __restrict__ staging, int nedges) {
    __shared__ int lcnt[KPAD];
    const int b = blockIdx.x, tid = threadIdx.x;
    for (int k = tid; k < KPAD; k += 256) lcnt[k] = gbase[(k << 8) + b];
    __syncthreads();
    const int chunk = (nedges + PB - 1) / PB;
    const int beg = b * chunk;
    const int end = min(beg + chunk, nedges);
    for (int e = beg + tid; e < end; e += 256) {
        int r   = rows[e];
        int pos = atomicAdd(&lcnt[r >> 8], 1);
        staging[pos] = make_int2(cols[e] | ((r & 255) << 17), __float_as_int(vals[e]));
    }
}

// One block per 256-row bucket, single pass over staging: edges cached in
// LDS (cap PCAP, fallback re-reads global), LDS row-hist + block scan ->
// row_ptr + cursors, scatter to exact CSR slots (single-XCD ~40 KB window).
__global__ void __launch_bounds__(256)
lgcn_place(const int* __restrict__ gbase, const int2* __restrict__ staging,
           int* __restrict__ row_ptr, int2* __restrict__ edges, int n, int nbuck) {
    __shared__ int rcnt[RPB];
    __shared__ int cur[RPB];
    __shared__ int wsum[4];
    __shared__ int2 cache[PCAP];
    const int k    = blockIdx.x;
    const int tid  = threadIdx.x;
    const int lane = tid & 63;
    const int wid  = tid >> 6;
    const int base = gbase[k << 8];          // gbase[k][0]
    const int next = gbase[(k + 1) << 8];    // gbase[k+1][0]
    const int cnt  = next - base;
    const bool fit = (cnt <= PCAP);

    rcnt[tid] = 0;
    __syncthreads();
    if (fit) {
        for (int i = tid; i < cnt; i += 256) {
            int2 p = staging[base + i];
            cache[i] = p;
            atomicAdd(&rcnt[(p.x >> 17) & 255], 1);
        }
    } else {
        for (int i = base + tid; i < next; i += 256)
            atomicAdd(&rcnt[(staging[i].x >> 17) & 255], 1);
    }
    __syncthreads();

    // block-exclusive scan of the 256 row counts
    const int v = rcnt[tid];
    int incl = v;
    #pragma unroll
    for (int off = 1; off < 64; off <<= 1) {
        int t = __shfl_up(incl, off, 64);
        if (lane >= off) incl += t;
    }
    if (lane == 63) wsum[wid] = incl;
    __syncthreads();
    int woff = 0;
    #pragma unroll
    for (int w = 0; w < 4; ++w) woff += (w < wid) ? wsum[w] : 0;
    const int ex = woff + incl - v;

    cur[tid] = base + ex;
    const int r = (k << 8) + tid;
    if (r < n) row_ptr[r] = base + ex;
    if (k == nbuck - 1 && tid == 0) row_ptr[n] = next;
    __syncthreads();

    if (fit) {
        for (int i = tid; i < cnt; i += 256) {
            int2 p  = cache[i];
            int pos = atomicAdd(&cur[(p.x >> 17) & 255], 1);
            edges[pos] = make_int2(p.x & 0x1FFFF, p.y);
        }
    } else {
        for (int i = base + tid; i < next; i += 256) {
            int2 p  = staging[i];
            int pos = atomicAdd(&cur[(p.x >> 17) & 255], 1);
            edges[pos] = make_int2(p.x & 0x1FFFF, p.y);
        }
    }
}

// Wide-gather SpMM (unchanged). One wave per row. lane = 16*g + l:
//   g = lane>>4 : edge slot (4 edges per gather instruction)
//   l = lane&15 : dim quarter, dims [8l, 8l+8) as one int4 of 8 fp16.
// mode 0: xout[row] = fp16(s)
// mode 1: out[row]  = (emb[row] + x1[row] + x2[row] + s) * 0.25  (fp32)
__global__ void __launch_bounds__(256)
lgcn_spmm(const int* __restrict__ row_ptr, const int2* __restrict__ edges,
          const __half2* __restrict__ xin, __half2* __restrict__ xout,
          const float2* __restrict__ emb, const __half2* __restrict__ x1h,
          float2* __restrict__ out, int n, int mode) {
    const int wave = blockIdx.x * 4 + (threadIdx.x >> 6);
    const int lane = threadIdx.x & 63;
    const int g    = lane >> 4;
    const int l    = lane & 15;
    if (wave >= n) return;
    const int beg = row_ptr[wave];
    const int end = row_ptr[wave + 1];

    const int4* __restrict__ x4 = (const int4*)xin;  // 16 int4 per row

    float a0 = 0.f, a1 = 0.f, a2 = 0.f, a3 = 0.f;
    float a4 = 0.f, a5 = 0.f, a6 = 0.f, a7 = 0.f;

#define FMA8(Q, V)                                                        \
    {                                                                     \
        float2 f0 = __half22float2(*(const __half2*)&(Q).x);              \
        float2 f1 = __half22float2(*(const __half2*)&(Q).y);              \
        float2 f2 = __half22float2(*(const __half2*)&(Q).z);              \
        float2 f3 = __half22float2(*(const __half2*)&(Q).w);              \
        a0 = fmaf((V), f0.x, a0); a1 = fmaf((V), f0.y, a1);               \
        a2 = fmaf((V), f1.x, a2); a3 = fmaf((V), f1.y, a3);               \
        a4 = fmaf((V), f2.x, a4); a5 = fmaf((V), f2.y, a5);               \
        a6 = fmaf((V), f3.x, a6); a7 = fmaf((V), f3.y, a7);               \
    }

    int e = beg;
    // main: 16 edges per iteration = 4 independent wide gathers (64 lines).
    for (; e + 16 <= end; e += 16) {
        int2 d0 = edges[e + g];
        int2 d1 = edges[e + 4 + g];
        int2 d2 = edges[e + 8 + g];
        int2 d3 = edges[e + 12 + g];
        int4 q0 = x4[d0.x * 16 + l];
        int4 q1 = x4[d1.x * 16 + l];
        int4 q2 = x4[d2.x * 16 + l];
        int4 q3 = x4[d3.x * 16 + l];
        FMA8(q0, __int_as_float(d0.y));
        FMA8(q1, __int_as_float(d1.y));
        FMA8(q2, __int_as_float(d2.y));
        FMA8(q3, __int_as_float(d3.y));
    }
    // mid tail: 8 edges.
    for (; e + 8 <= end; e += 8) {
        int2 d0 = edges[e + g];
        int2 d1 = edges[e + 4 + g];
        int4 q0 = x4[d0.x * 16 + l];
        int4 q1 = x4[d1.x * 16 + l];
        FMA8(q0, __int_as_float(d0.y));
        FMA8(q1, __int_as_float(d1.y));
    }
    // masked tail: up to 4 edges per iteration; masked lanes gather row 0
    // (hot line) with v = 0 -> no contribution.
    for (; e < end; e += 4) {
        const int ee = e + g;
        int2 d = (ee < end) ? edges[ee] : make_int2(0, 0);
        int4 q = x4[d.x * 16 + l];
        FMA8(q, __int_as_float(d.y));
    }
#undef FMA8

    // reduce across the 4 edge slots (groups differ in lane bits 4,5)
    a0 += __shfl_xor(a0, 16); a0 += __shfl_xor(a0, 32);
    a1 += __shfl_xor(a1, 16); a1 += __shfl_xor(a1, 32);
    a2 += __shfl_xor(a2, 16); a2 += __shfl_xor(a2, 32);
    a3 += __shfl_xor(a3, 16); a3 += __shfl_xor(a3, 32);
    a4 += __shfl_xor(a4, 16); a4 += __shfl_xor(a4, 32);
    a5 += __shfl_xor(a5, 16); a5 += __shfl_xor(a5, 32);
    a6 += __shfl_xor(a6, 16); a6 += __shfl_xor(a6, 32);
    a7 += __shfl_xor(a7, 16); a7 += __shfl_xor(a7, 32);

    if (mode == 0) {
        if (g == 0) {
            int4 r;
            __half2 h0 = __float22half2_rn(make_float2(a0, a1));
            __half2 h1 = __float22half2_rn(make_float2(a2, a3));
            __half2 h2 = __float22half2_rn(make_float2(a4, a5));
            __half2 h3 = __float22half2_rn(make_float2(a6, a7));
            r.x = *(const int*)&h0; r.y = *(const int*)&h1;
            r.z = *(const int*)&h2; r.w = *(const int*)&h3;
            ((int4*)xout)[wave * 16 + l] = r;
        }
    } else {
        float4 e0 = ((const float4*)emb)[wave * 32 + l * 2 + 0];
        float4 e1 = ((const float4*)emb)[wave * 32 + l * 2 + 1];
        int4  h1q = ((const int4*)x1h)[wave * 16 + l];
        int4  h2q = ((const int4*)xin)[wave * 16 + l];
        float2 b0 = __half22float2(*(const __half2*)&h1q.x);
        float2 b1 = __half22float2(*(const __half2*)&h1q.y);
        float2 b2 = __half22float2(*(const __half2*)&h1q.z);
        float2 b3 = __half22float2(*(const __half2*)&h1q.w);
        float2 c0 = __half22float2(*(const __half2*)&h2q.x);
        float2 c1 = __half22float2(*(const __half2*)&h2q.y);
        float2 c2 = __half22float2(*(const __half2*)&h2q.z);
        float2 c3 = __half22float2(*(const __half2*)&h2q.w);
        if (g == 0) {
            float4 r0, r1;
            r0.x = (e0.x + b0.x + c0.x + a0) * 0.25f;
            r0.y = (e0.y + b0.y + c0.y + a1) * 0.25f;
            r0.z = (e0.z + b1.x + c1.x + a2) * 0.25f;
            r0.w = (e0.w + b1.y + c1.y + a3) * 0.25f;
            r1.x = (e1.x + b2.x + c2.x + a4) * 0.25f;
            r1.y = (e1.y + b2.y + c2.y + a5) * 0.25f;
            r1.z = (e1.z + b3.x + c3.x + a6) * 0.25f;
            r1.w = (e1.w + b3.y + c3.y + a7) * 0.25f;
            ((float4*)out)[wave * 32 + l * 2 + 0] = r0;
            ((float4*)out)[wave * 32 + l * 2 + 1] = r1;
        }
    }
}

extern "C" void kernel_launch(void* const* d_in, const int* in_sizes, int n_in,
                              void* d_out, int out_size, void* d_ws, size_t ws_size,
                              hipStream_t stream) {
    const float* emb  = (const float*)d_in[0];
    const int*   rows = (const int*)d_in[1];
    const int*   cols = (const int*)d_in[2];
    const float* vals = (const float*)d_in[3];

    const int  n_nodes = in_sizes[0] / DIM;    // 100000
    const int  nedges  = in_sizes[1];          // 2000000
    const long nd      = (long)n_nodes * DIM;  // 12.8M

    char* ws = (char*)d_ws;
    size_t off = 0;
    __half2* bufA = (__half2*)(ws + off); off = align_up(off + nd * 2, 256);   // x0 then x2
    __half2* bufB = (__half2*)(ws + off); off = align_up(off + nd * 2, 256);   // x1 / staging
    int2* edges   = (int2*)(ws + off);    off = align_up(off + (size_t)nedges * 8, 256);
    int* row_ptr  = (int*)(ws + off);     off = align_up(off + (size_t)(n_nodes + 1) * 4, 256);
    int* ghist    = (int*)(ws + off);     off = align_up(off + (size_t)NSCAN * 4, 256);
    int* gbase    = (int*)(ws + off);     off = align_up(off + ((size_t)NSCAN + 1) * 4, 256);
    unsigned long long* tstat = (unsigned long long*)(ws + off);
    off = align_up(off + (size_t)NTILES * 8, 256);
    float2* out   = (float2*)d_out;

    int2* staging = (int2*)bufB;  // bufB is dead until spmm layer 1

    const int BS = 256;
    const int n2      = (int)(nd / 2);
    const int grid_c  = (n2 + BS - 1) / BS;               // 25000 conv blocks
    const int nbuck   = (n_nodes + RPB - 1) / RPB;        // 391 (<= KPAD)
    const int grid_s  = (n_nodes + 3) / 4;                // 4 rows per block

    // conv + histogram + scan-status zero (one kernel)
    lgcn_prep<<<PB + 1 + grid_c, BS, 0, stream>>>((const float2*)emb, bufA, n2,
                                                  rows, ghist, nedges, tstat);
    // single-kernel decoupled-lookback scan (wave-parallel lookback, fixed)
    lgcn_scan<<<NTILES, BS, 0, stream>>>(ghist, gbase, tstat, NSCAN);
    // deterministic partition + single-pass place
    lgcn_part<<<PB, BS, 0, stream>>>(rows, cols, vals, gbase, staging, nedges);
    lgcn_place<<<nbuck, BS, 0, stream>>>(gbase, staging, row_ptr, edges, n_nodes, nbuck);

    // 3 SpMM layers: x1 = A x0, x2 = A x1, out = (emb + x1 + x2 + A x2)/4
    lgcn_spmm<<<grid_s, BS, 0, stream>>>(row_ptr, edges, bufA, bufB,
                                         nullptr, nullptr, nullptr, n_nodes, 0);
    lgcn_spmm<<<grid_s, BS, 0, stream>>>(row_ptr, edges, bufB, bufA,
                                         nullptr, nullptr, nullptr, n_nodes, 0);
    lgcn_spmm<<<grid_s, BS, 0, stream>>>(row_ptr, edges, bufA, nullptr,
                                         (const float2*)emb, bufB, out, n_nodes, 1);
}

// Round 7
// 387.850 us; speedup vs baseline: 1.0829x; 1.0554x over previous
//
#include <hip/hip_runtime.h>
#include <hip/hip_fp16.h>

// LightGCN propagation on MI355X — round 10: build-phase occupancy fix.
// N = 100000 nodes, D = 128, E = 2,000,000 edges, 3 layers.
//
// Round-9 post-mortem: spmm frozen at 86.2 us x3 (279 MB fetch, L2-miss-path
// bound). Non-spmm residual = 150 us vs ~50 us of traffic -> latency-bound:
// lgcn_part ran 256 blocks x 256 thr = 1 wave/SIMD (3% occupancy) with a
// dependent load->LDS-atomic->scatter chain; place 1-2 waves/SIMD; prep-hist
// same. Round 10: SAME algorithm, SAME chunk/bucket geometry (PB=256 chunks,
// 512 buckets, identical gbase/staging layout + write-locality), but prep /
// part / place use 1024-thread blocks -> 16 waves/block, 4x thread-level
// parallelism per chunk. scan + all three spmm byte-identical to round 9.
//
// ws layout (256 B aligned):
//   bufA : nd fp16 (x0, later x2)                 25.6 MB
//   bufB : nd fp16 (x1; int2 staging during build) 25.6 MB
//   edges: E int2                                  16 MB
//   row_ptr(n+1), ghist(512*256), gbase(+1), tstat ~1.5 MB

#define DIM  128
#define PB   256   // partition chunks (and hist/part blocks)
#define KPAD 512   // padded bucket count (nbuck = ceil(n/256) = 391 <= 512)
#define RPB  256   // rows per bucket
#define NSCAN (KPAD * PB)     // 131072
#define NTILES (NSCAN / 1024) // 128 scan tiles
#define PCAP 7168             // place LDS edge cache (56 KB); avg bucket 5120

static inline size_t align_up(size_t v, size_t a) { return (v + a - 1) & ~(a - 1); }

// Fused: conv (emb->fp16 x0), per-chunk coarse histogram, scan-status zero.
// 1024 threads/block.
__global__ void __launch_bounds__(1024)
lgcn_prep(const float2* __restrict__ emb, __half2* __restrict__ x0, int n2,
          const int* __restrict__ rows, int* __restrict__ ghist, int nedges,
          unsigned long long* __restrict__ tstat) {
    __shared__ int h[KPAD];
    const int b = blockIdx.x, tid = threadIdx.x;
    if (b < PB) {
        // histogram role: block b owns edges [b*chunk, (b+1)*chunk)
        for (int k = tid; k < KPAD; k += 1024) h[k] = 0;
        __syncthreads();
        const int chunk = (nedges + PB - 1) / PB;
        const int beg = b * chunk;
        const int end = min(beg + chunk, nedges);
        for (int e = beg + tid; e < end; e += 1024)
            atomicAdd(&h[rows[e] >> 8], 1);
        __syncthreads();
        for (int k = tid; k < KPAD; k += 1024) ghist[(k << 8) + b] = h[k];
    } else if (b == PB) {
        if (tid < NTILES) tstat[tid] = 0ull;
    } else {
        const int i = (b - PB - 1) * 1024 + tid;
        if (i < n2) x0[i] = __float22half2_rn(emb[i]);
    }
}

// Single-kernel decoupled-lookback exclusive scan of ghist -> gbase.
// (unchanged from round 9; wave-parallel lookback, window-miss summing fixed)
__global__ void __launch_bounds__(256)
lgcn_scan(const int* __restrict__ ghist, int* __restrict__ gbase,
          unsigned long long* __restrict__ tstat, int nscan) {
    __shared__ int wsum[4];
    __shared__ int btot_s, prev_s;
    const int tile = blockIdx.x;
    const int tid  = threadIdx.x;
    const int lane = tid & 63;
    const int wid  = tid >> 6;
    const int i0   = tile * 1024 + tid * 4;

    int4 c = *(const int4*)(ghist + i0);
    const int t1 = c.x + c.y, t2 = t1 + c.z, tsum = t2 + c.w;

    int incl = tsum;
    #pragma unroll
    for (int off = 1; off < 64; off <<= 1) {
        int t = __shfl_up(incl, off, 64);
        if (lane >= off) incl += t;
    }
    if (lane == 63) wsum[wid] = incl;
    __syncthreads();
    int woff = 0;
    #pragma unroll
    for (int w = 0; w < 4; ++w) woff += (w < wid) ? wsum[w] : 0;
    const int ex = woff + incl - tsum;
    if (tid == 255) btot_s = woff + incl;
    __syncthreads();
    const int btot = btot_s;

    if (tile == 0) {
        if (tid == 0) {
            __hip_atomic_store(&tstat[0],
                (((unsigned long long)(unsigned)btot) << 32) | 2ull,
                __ATOMIC_RELEASE, __HIP_MEMORY_SCOPE_AGENT);
            prev_s = 0;
        }
    } else if (wid == 0) {
        if (lane == 0)
            __hip_atomic_store(&tstat[tile],
                (((unsigned long long)(unsigned)btot) << 32) | 1ull,
                __ATOMIC_RELEASE, __HIP_MEMORY_SCOPE_AGENT);
        int run = 0;
        int base_p = tile - 1;   // nearest predecessor handled by lane 0
        while (true) {
            const int p = base_p - lane;
            unsigned long long st;
            if (p >= 0) {
                do {
                    st = __hip_atomic_load(&tstat[p],
                        __ATOMIC_ACQUIRE, __HIP_MEMORY_SCOPE_AGENT);
                    if (((unsigned)st & 3u) != 0u) break;
                    __builtin_amdgcn_s_sleep(1);
                } while (true);
            } else {
                st = 2ull;  // virtual tile: value 0, inclusive
            }
            const unsigned f = (unsigned)st & 3u;
            const int v = (int)(unsigned)(st >> 32);
            const unsigned long long inc_mask = __ballot(f == 2u);
            int contrib;
            if (inc_mask != 0ull) {
                const int l_star = (int)(__ffsll((long long)inc_mask) - 1);
                contrib = (lane <= l_star) ? v : 0;   // aggregates before + the inclusive
            } else {
                contrib = v;                          // whole window is aggregates
            }
            #pragma unroll
            for (int off = 1; off < 64; off <<= 1)
                contrib += __shfl_xor(contrib, off);
            run += contrib;
            if (inc_mask != 0ull) break;
            base_p -= 64;
        }
        if (lane == 0) {
            __hip_atomic_store(&tstat[tile],
                (((unsigned long long)(unsigned)(run + btot)) << 32) | 2ull,
                __ATOMIC_RELEASE, __HIP_MEMORY_SCOPE_AGENT);
            prev_s = run;
        }
    }
    __syncthreads();
    const int pv = prev_s;

    int4 o;
    o.x = pv + ex;
    o.y = pv + ex + c.x;
    o.z = pv + ex + t1;
    o.w = pv + ex + t2;
    *(int4*)(gbase + i0) = o;
    if (tile == gridDim.x - 1 && tid == 255) gbase[nscan] = pv + btot;
}

// Deterministic partition: block b re-reads its chunk; LDS counters start at
// gbase[k][b]; each edge goes to a contiguous (block,bucket) range written by
// this CU only. 1024 threads/block (16 waves -> latency hiding).
__global__ void __launch_bounds__(1024)
lgcn_part(const int* __restrict__ rows, const int* __restrict__ cols,
          const float* __restrict__ vals, const int* __restrict__ gbase,
          int2* __restrict__ staging, int nedges) {
    __shared__ int lcnt[KPAD];
    const int b = blockIdx.x, tid = threadIdx.x;
    for (int k = tid; k < KPAD; k += 1024) lcnt[k] = gbase[(k << 8) + b];
    __syncthreads();
    const int chunk = (nedges + PB - 1) / PB;
    const int beg = b * chunk;
    const int end = min(beg + chunk, nedges);
    for (int e = beg + tid; e < end; e += 1024) {
        int r   = rows[e];
        int pos = atomicAdd(&lcnt[r >> 8], 1);
        staging[pos] = make_int2(cols[e] | ((r & 255) << 17), __float_as_int(vals[e]));
    }
}

// One block per 256-row bucket, single pass over staging: edges cached in
// LDS (cap PCAP, fallback re-reads global), LDS row-hist + block scan ->
// row_ptr + cursors, scatter to exact CSR slots. 1024 threads/block.
__global__ void __launch_bounds__(1024)
lgcn_place(const int* __restrict__ gbase, const int2* __restrict__ staging,
           int* __restrict__ row_ptr, int2* __restrict__ edges, int n, int nbuck) {
    __shared__ int rcnt[RPB];
    __shared__ int cur[RPB];
    __shared__ int wsum[4];
    __shared__ int2 cache[PCAP];
    const int k    = blockIdx.x;
    const int tid  = threadIdx.x;
    const int base = gbase[k << 8];          // gbase[k][0]
    const int next = gbase[(k + 1) << 8];    // gbase[k+1][0]
    const int cnt  = next - base;
    const bool fit = (cnt <= PCAP);

    if (tid < RPB) rcnt[tid] = 0;
    __syncthreads();
    if (fit) {
        for (int i = tid; i < cnt; i += 1024) {
            int2 p = staging[base + i];
            cache[i] = p;
            atomicAdd(&rcnt[(p.x >> 17) & 255], 1);
        }
    } else {
        for (int i = base + tid; i < next; i += 1024)
            atomicAdd(&rcnt[(staging[i].x >> 17) & 255], 1);
    }
    __syncthreads();

    // block-exclusive scan of the 256 row counts (first 4 waves)
    if (tid < RPB) {
        const int lane = tid & 63;
        const int wid  = tid >> 6;
        const int v = rcnt[tid];
        int incl = v;
        #pragma unroll
        for (int off = 1; off < 64; off <<= 1) {
            int t = __shfl_up(incl, off, 64);
            if (lane >= off) incl += t;
        }
        if (lane == 63) wsum[wid] = incl;
        __syncthreads();
        int woff = 0;
        #pragma unroll
        for (int w = 0; w < 4; ++w) woff += (w < wid) ? wsum[w] : 0;
        const int ex = woff + incl - v;

        cur[tid] = base + ex;
        const int r = (k << 8) + tid;
        if (r < n) row_ptr[r] = base + ex;
        if (k == nbuck - 1 && tid == 0) row_ptr[n] = next;
    } else {
        __syncthreads();   // match the scan's barrier
    }
    __syncthreads();

    if (fit) {
        for (int i = tid; i < cnt; i += 1024) {
            int2 p  = cache[i];
            int pos = atomicAdd(&cur[(p.x >> 17) & 255], 1);
            edges[pos] = make_int2(p.x & 0x1FFFF, p.y);
        }
    } else {
        for (int i = base + tid; i < next; i += 1024) {
            int2 p  = staging[i];
            int pos = atomicAdd(&cur[(p.x >> 17) & 255], 1);
            edges[pos] = make_int2(p.x & 0x1FFFF, p.y);
        }
    }
}

// Wide-gather SpMM (unchanged). One wave per row. lane = 16*g + l:
//   g = lane>>4 : edge slot (4 edges per gather instruction)
//   l = lane&15 : dim quarter, dims [8l, 8l+8) as one int4 of 8 fp16.
// mode 0: xout[row] = fp16(s)
// mode 1: out[row]  = (emb[row] + x1[row] + x2[row] + s) * 0.25  (fp32)
__global__ void __launch_bounds__(256)
lgcn_spmm(const int* __restrict__ row_ptr, const int2* __restrict__ edges,
          const __half2* __restrict__ xin, __half2* __restrict__ xout,
          const float2* __restrict__ emb, const __half2* __restrict__ x1h,
          float2* __restrict__ out, int n, int mode) {
    const int wave = blockIdx.x * 4 + (threadIdx.x >> 6);
    const int lane = threadIdx.x & 63;
    const int g    = lane >> 4;
    const int l    = lane & 15;
    if (wave >= n) return;
    const int beg = row_ptr[wave];
    const int end = row_ptr[wave + 1];

    const int4* __restrict__ x4 = (const int4*)xin;  // 16 int4 per row

    float a0 = 0.f, a1 = 0.f, a2 = 0.f, a3 = 0.f;
    float a4 = 0.f, a5 = 0.f, a6 = 0.f, a7 = 0.f;

#define FMA8(Q, V)                                                        \
    {                                                                     \
        float2 f0 = __half22float2(*(const __half2*)&(Q).x);              \
        float2 f1 = __half22float2(*(const __half2*)&(Q).y);              \
        float2 f2 = __half22float2(*(const __half2*)&(Q).z);              \
        float2 f3 = __half22float2(*(const __half2*)&(Q).w);              \
        a0 = fmaf((V), f0.x, a0); a1 = fmaf((V), f0.y, a1);               \
        a2 = fmaf((V), f1.x, a2); a3 = fmaf((V), f1.y, a3);               \
        a4 = fmaf((V), f2.x, a4); a5 = fmaf((V), f2.y, a5);               \
        a6 = fmaf((V), f3.x, a6); a7 = fmaf((V), f3.y, a7);               \
    }

    int e = beg;
    // main: 16 edges per iteration = 4 independent wide gathers (64 lines).
    for (; e + 16 <= end; e += 16) {
        int2 d0 = edges[e + g];
        int2 d1 = edges[e + 4 + g];
        int2 d2 = edges[e + 8 + g];
        int2 d3 = edges[e + 12 + g];
        int4 q0 = x4[d0.x * 16 + l];
        int4 q1 = x4[d1.x * 16 + l];
        int4 q2 = x4[d2.x * 16 + l];
        int4 q3 = x4[d3.x * 16 + l];
        FMA8(q0, __int_as_float(d0.y));
        FMA8(q1, __int_as_float(d1.y));
        FMA8(q2, __int_as_float(d2.y));
        FMA8(q3, __int_as_float(d3.y));
    }
    // mid tail: 8 edges.
    for (; e + 8 <= end; e += 8) {
        int2 d0 = edges[e + g];
        int2 d1 = edges[e + 4 + g];
        int4 q0 = x4[d0.x * 16 + l];
        int4 q1 = x4[d1.x * 16 + l];
        FMA8(q0, __int_as_float(d0.y));
        FMA8(q1, __int_as_float(d1.y));
    }
    // masked tail: up to 4 edges per iteration; masked lanes gather row 0
    // (hot line) with v = 0 -> no contribution.
    for (; e < end; e += 4) {
        const int ee = e + g;
        int2 d = (ee < end) ? edges[ee] : make_int2(0, 0);
        int4 q = x4[d.x * 16 + l];
        FMA8(q, __int_as_float(d.y));
    }
#undef FMA8

    // reduce across the 4 edge slots (groups differ in lane bits 4,5)
    a0 += __shfl_xor(a0, 16); a0 += __shfl_xor(a0, 32);
    a1 += __shfl_xor(a1, 16); a1 += __shfl_xor(a1, 32);
    a2 += __shfl_xor(a2, 16); a2 += __shfl_xor(a2, 32);
    a3 += __shfl_xor(a3, 16); a3 += __shfl_xor(a3, 32);
    a4 += __shfl_xor(a4, 16); a4 += __shfl_xor(a4, 32);
    a5 += __shfl_xor(a5, 16); a5 += __shfl_xor(a5, 32);
    a6 += __shfl_xor(a6, 16); a6 += __shfl_xor(a6, 32);
    a7 += __shfl_xor(a7, 16); a7 += __shfl_xor(a7, 32);

    if (mode == 0) {
        if (g == 0) {
            int4 r;
            __half2 h0 = __float22half2_rn(make_float2(a0, a1));
            __half2 h1 = __float22half2_rn(make_float2(a2, a3));
            __half2 h2 = __float22half2_rn(make_float2(a4, a5));
            __half2 h3 = __float22half2_rn(make_float2(a6, a7));
            r.x = *(const int*)&h0; r.y = *(const int*)&h1;
            r.z = *(const int*)&h2; r.w = *(const int*)&h3;
            ((int4*)xout)[wave * 16 + l] = r;
        }
    } else {
        float4 e0 = ((const float4*)emb)[wave * 32 + l * 2 + 0];
        float4 e1 = ((const float4*)emb)[wave * 32 + l * 2 + 1];
        int4  h1q = ((const int4*)x1h)[wave * 16 + l];
        int4  h2q = ((const int4*)xin)[wave * 16 + l];
        float2 b0 = __half22float2(*(const __half2*)&h1q.x);
        float2 b1 = __half22float2(*(const __half2*)&h1q.y);
        float2 b2 = __half22float2(*(const __half2*)&h1q.z);
        float2 b3 = __half22float2(*(const __half2*)&h1q.w);
        float2 c0 = __half22float2(*(const __half2*)&h2q.x);
        float2 c1 = __half22float2(*(const __half2*)&h2q.y);
        float2 c2 = __half22float2(*(const __half2*)&h2q.z);
        float2 c3 = __half22float2(*(const __half2*)&h2q.w);
        if (g == 0) {
            float4 r0, r1;
            r0.x = (e0.x + b0.x + c0.x + a0) * 0.25f;
            r0.y = (e0.y + b0.y + c0.y + a1) * 0.25f;
            r0.z = (e0.z + b1.x + c1.x + a2) * 0.25f;
            r0.w = (e0.w + b1.y + c1.y + a3) * 0.25f;
            r1.x = (e1.x + b2.x + c2.x + a4) * 0.25f;
            r1.y = (e1.y + b2.y + c2.y + a5) * 0.25f;
            r1.z = (e1.z + b3.x + c3.x + a6) * 0.25f;
            r1.w = (e1.w + b3.y + c3.y + a7) * 0.25f;
            ((float4*)out)[wave * 32 + l * 2 + 0] = r0;
            ((float4*)out)[wave * 32 + l * 2 + 1] = r1;
        }
    }
}

extern "C" void kernel_launch(void* const* d_in, const int* in_sizes, int n_in,
                              void* d_out, int out_size, void* d_ws, size_t ws_size,
                              hipStream_t stream) {
    const float* emb  = (const float*)d_in[0];
    const int*   rows = (const int*)d_in[1];
    const int*   cols = (const int*)d_in[2];
    const float* vals = (const float*)d_in[3];

    const int  n_nodes = in_sizes[0] / DIM;    // 100000
    const int  nedges  = in_sizes[1];          // 2000000
    const long nd      = (long)n_nodes * DIM;  // 12.8M

    char* ws = (char*)d_ws;
    size_t off = 0;
    __half2* bufA = (__half2*)(ws + off); off = align_up(off + nd * 2, 256);   // x0 then x2
    __half2* bufB = (__half2*)(ws + off); off = align_up(off + nd * 2, 256);   // x1 / staging
    int2* edges   = (int2*)(ws + off);    off = align_up(off + (size_t)nedges * 8, 256);
    int* row_ptr  = (int*)(ws + off);     off = align_up(off + (size_t)(n_nodes + 1) * 4, 256);
    int* ghist    = (int*)(ws + off);     off = align_up(off + (size_t)NSCAN * 4, 256);
    int* gbase    = (int*)(ws + off);     off = align_up(off + ((size_t)NSCAN + 1) * 4, 256);
    unsigned long long* tstat = (unsigned long long*)(ws + off);
    off = align_up(off + (size_t)NTILES * 8, 256);
    float2* out   = (float2*)d_out;

    int2* staging = (int2*)bufB;  // bufB is dead until spmm layer 1

    const int BS = 256;
    const int n2      = (int)(nd / 2);
    const int grid_c  = (n2 + 1023) / 1024;               // conv blocks (1024 thr)
    const int nbuck   = (n_nodes + RPB - 1) / RPB;        // 391 (<= KPAD)
    const int grid_s  = (n_nodes + 3) / 4;                // 4 rows per block

    // conv + histogram + scan-status zero (one kernel, 1024 thr/block)
    lgcn_prep<<<PB + 1 + grid_c, 1024, 0, stream>>>((const float2*)emb, bufA, n2,
                                                    rows, ghist, nedges, tstat);
    // single-kernel decoupled-lookback scan (wave-parallel lookback)
    lgcn_scan<<<NTILES, BS, 0, stream>>>(ghist, gbase, tstat, NSCAN);
    // deterministic partition + single-pass place (1024 thr/block)
    lgcn_part<<<PB, 1024, 0, stream>>>(rows, cols, vals, gbase, staging, nedges);
    lgcn_place<<<nbuck, 1024, 0, stream>>>(gbase, staging, row_ptr, edges, n_nodes, nbuck);

    // 3 SpMM layers: x1 = A x0, x2 = A x1, out = (emb + x1 + x2 + A x2)/4
    lgcn_spmm<<<grid_s, BS, 0, stream>>>(row_ptr, edges, bufA, bufB,
                                         nullptr, nullptr, nullptr, n_nodes, 0);
    lgcn_spmm<<<grid_s, BS, 0, stream>>>(row_ptr, edges, bufB, bufA,
                                         nullptr, nullptr, nullptr, n_nodes, 0);
    lgcn_spmm<<<grid_s, BS, 0, stream>>>(row_ptr, edges, bufA, nullptr,
                                         (const float2*)emb, bufB, out, n_nodes, 1);
}

// Round 9
// 355.973 us; speedup vs baseline: 1.1799x; 1.0895x over previous
//
#include <hip/hip_runtime.h>
#include <hip/hip_fp16.h>

// LightGCN propagation on MI355X — round 12: int8 gather (r11 compile fix).
// N = 100000 nodes, D = 128, E = 2,000,000 edges, 3 layers.
//
// Round-11 failed to compile: __builtin_amdgcn_cvt_pkrtz returns
// __fp16-vector, not _Float16-vector. Replaced with __float2half2_rn(SV)
// (single f32->f16 convert + broadcast). Everything else identical to r11:
//   - x stored int8 + per-row scale: row = 128 B -> logical gather halves
//     (512 -> 256 MB); int8 RMS err ~0.8% of rowmax (est absmax ~7e-4
//     vs 2.6e-3 threshold);
//   - dequant: v_perm builds fp16(1024+q) pairs from bytes, +(-1152)
//     centers to exact (q-128), hfma2 with sv = s*val*256 (vals pre-scaled
//     x256 in build; 1/256 descale at readout);
//   - build pipeline: deterministic two-pass sort (r5) + lookback scan (r9)
//     + 1024-thread blocks (r10); conv is wave-per-row quantization.
//
// ws layout (256 B aligned):
//   x0q/x2q : nd int8                            12.8 MB
//   x1q     : nd int8                            12.8 MB
//   edges   : E int2 (val pre-scaled x256)        16 MB
//   staging : E int2                              16 MB
//   scA, scB: n floats (row scales)              0.8 MB
//   row_ptr(n+1), ghist, gbase(+1), tstat        ~1.5 MB

#define DIM  128
#define PB   256   // partition chunks (and hist/part blocks)
#define KPAD 512   // padded bucket count (nbuck = ceil(n/256) = 391 <= 512)
#define RPB  256   // rows per bucket
#define NSCAN (KPAD * PB)     // 131072
#define NTILES (NSCAN / 1024) // 128 scan tiles
#define PCAP 7168             // place LDS edge cache (56 KB); avg bucket 5120

static inline size_t align_up(size_t v, size_t a) { return (v + a - 1) & ~(a - 1); }

union H2 { unsigned u; __half2 h; };

// Fused: wave-per-row quantizing conv (emb fp32 -> int8 + scale), per-chunk
// coarse histogram, scan-status zero. 1024 threads/block.
__global__ void __launch_bounds__(1024)
lgcn_prep(const float2* __restrict__ emb2, int* __restrict__ x0q,
          float* __restrict__ sc0, int n,
          const int* __restrict__ rows, int* __restrict__ ghist, int nedges,
          unsigned long long* __restrict__ tstat) {
    __shared__ int h[KPAD];
    const int b = blockIdx.x, tid = threadIdx.x;
    if (b < PB) {
        for (int k = tid; k < KPAD; k += 1024) h[k] = 0;
        __syncthreads();
        const int chunk = (nedges + PB - 1) / PB;
        const int beg = b * chunk;
        const int end = min(beg + chunk, nedges);
        for (int e = beg + tid; e < end; e += 1024)
            atomicAdd(&h[rows[e] >> 8], 1);
        __syncthreads();
        for (int k = tid; k < KPAD; k += 1024) ghist[(k << 8) + b] = h[k];
    } else if (b == PB) {
        if (tid < NTILES) tstat[tid] = 0ull;
    } else {
        // quant-conv: one wave per row; lane holds dims (2*lane, 2*lane+1)
        const int wid  = tid >> 6;
        const int lane = tid & 63;
        const int row  = (b - PB - 1) * 16 + wid;
        if (row >= n) return;
        float2 v = emb2[(size_t)row * 64 + lane];
        float m = fmaxf(fabsf(v.x), fabsf(v.y));
        #pragma unroll
        for (int off = 1; off < 64; off <<= 1)
            m = fmaxf(m, __shfl_xor(m, off));
        const float inv = 127.0f / fmaxf(m, 1e-20f);
        int q0 = (int)(v.x * inv + 128.5f);
        int q1 = (int)(v.y * inv + 128.5f);
        q0 = min(max(q0, 0), 255); q1 = min(max(q1, 0), 255);
        ((unsigned short*)x0q)[(size_t)row * 64 + lane] =
            (unsigned short)(q0 | (q1 << 8));
        if (lane == 0) sc0[row] = m * (1.0f / 127.0f);
    }
}

// Single-kernel decoupled-lookback exclusive scan of ghist -> gbase.
// (unchanged; wave-parallel lookback)
__global__ void __launch_bounds__(256)
lgcn_scan(const int* __restrict__ ghist, int* __restrict__ gbase,
          unsigned long long* __restrict__ tstat, int nscan) {
    __shared__ int wsum[4];
    __shared__ int btot_s, prev_s;
    const int tile = blockIdx.x;
    const int tid  = threadIdx.x;
    const int lane = tid & 63;
    const int wid  = tid >> 6;
    const int i0   = tile * 1024 + tid * 4;

    int4 c = *(const int4*)(ghist + i0);
    const int t1 = c.x + c.y, t2 = t1 + c.z, tsum = t2 + c.w;

    int incl = tsum;
    #pragma unroll
    for (int off = 1; off < 64; off <<= 1) {
        int t = __shfl_up(incl, off, 64);
        if (lane >= off) incl += t;
    }
    if (lane == 63) wsum[wid] = incl;
    __syncthreads();
    int woff = 0;
    #pragma unroll
    for (int w = 0; w < 4; ++w) woff += (w < wid) ? wsum[w] : 0;
    const int ex = woff + incl - tsum;
    if (tid == 255) btot_s = woff + incl;
    __syncthreads();
    const int btot = btot_s;

    if (tile == 0) {
        if (tid == 0) {
            __hip_atomic_store(&tstat[0],
                (((unsigned long long)(unsigned)btot) << 32) | 2ull,
                __ATOMIC_RELEASE, __HIP_MEMORY_SCOPE_AGENT);
            prev_s = 0;
        }
    } else if (wid == 0) {
        if (lane == 0)
            __hip_atomic_store(&tstat[tile],
                (((unsigned long long)(unsigned)btot) << 32) | 1ull,
                __ATOMIC_RELEASE, __HIP_MEMORY_SCOPE_AGENT);
        int run = 0;
        int base_p = tile - 1;
        while (true) {
            const int p = base_p - lane;
            unsigned long long st;
            if (p >= 0) {
                do {
                    st = __hip_atomic_load(&tstat[p],
                        __ATOMIC_ACQUIRE, __HIP_MEMORY_SCOPE_AGENT);
                    if (((unsigned)st & 3u) != 0u) break;
                    __builtin_amdgcn_s_sleep(1);
                } while (true);
            } else {
                st = 2ull;
            }
            const unsigned f = (unsigned)st & 3u;
            const int v = (int)(unsigned)(st >> 32);
            const unsigned long long inc_mask = __ballot(f == 2u);
            int contrib;
            if (inc_mask != 0ull) {
                const int l_star = (int)(__ffsll((long long)inc_mask) - 1);
                contrib = (lane <= l_star) ? v : 0;
            } else {
                contrib = v;
            }
            #pragma unroll
            for (int off = 1; off < 64; off <<= 1)
                contrib += __shfl_xor(contrib, off);
            run += contrib;
            if (inc_mask != 0ull) break;
            base_p -= 64;
        }
        if (lane == 0) {
            __hip_atomic_store(&tstat[tile],
                (((unsigned long long)(unsigned)(run + btot)) << 32) | 2ull,
                __ATOMIC_RELEASE, __HIP_MEMORY_SCOPE_AGENT);
            prev_s = run;
        }
    }
    __syncthreads();
    const int pv = prev_s;

    int4 o;
    o.x = pv + ex;
    o.y = pv + ex + c.x;
    o.z = pv + ex + t1;
    o.w = pv + ex + t2;
    *(int4*)(gbase + i0) = o;
    if (tile == gridDim.x - 1 && tid == 255) gbase[nscan] = pv + btot;
}

// Deterministic partition (val pre-scaled x256).
__global__ void __launch_bounds__(1024)
lgcn_part(const int* __restrict__ rows, const int* __restrict__ cols,
          const float* __restrict__ vals, const int* __restrict__ gbase,
          int2* __restrict__ staging, int nedges) {
    __shared__ int lcnt[KPAD];
    const int b = blockIdx.x, tid = threadIdx.x;
    for (int k = tid; k < KPAD; k += 1024) lcnt[k] = gbase[(k << 8) + b];
    __syncthreads();
    const int chunk = (nedges + PB - 1) / PB;
    const int beg = b * chunk;
    const int end = min(beg + chunk, nedges);
    for (int e = beg + tid; e < end; e += 1024) {
        int r   = rows[e];
        int pos = atomicAdd(&lcnt[r >> 8], 1);
        staging[pos] = make_int2(cols[e] | ((r & 255) << 17),
                                 __float_as_int(vals[e] * 256.0f));
    }
}

// One block per 256-row bucket (unchanged).
__global__ void __launch_bounds__(1024)
lgcn_place(const int* __restrict__ gbase, const int2* __restrict__ staging,
           int* __restrict__ row_ptr, int2* __restrict__ edges, int n, int nbuck) {
    __shared__ int rcnt[RPB];
    __shared__ int cur[RPB];
    __shared__ int wsum[4];
    __shared__ int2 cache[PCAP];
    const int k    = blockIdx.x;
    const int tid  = threadIdx.x;
    const int base = gbase[k << 8];
    const int next = gbase[(k + 1) << 8];
    const int cnt  = next - base;
    const bool fit = (cnt <= PCAP);

    if (tid < RPB) rcnt[tid] = 0;
    __syncthreads();
    if (fit) {
        for (int i = tid; i < cnt; i += 1024) {
            int2 p = staging[base + i];
            cache[i] = p;
            atomicAdd(&rcnt[(p.x >> 17) & 255], 1);
        }
    } else {
        for (int i = base + tid; i < next; i += 1024)
            atomicAdd(&rcnt[(staging[i].x >> 17) & 255], 1);
    }
    __syncthreads();

    if (tid < RPB) {
        const int lane = tid & 63;
        const int wid  = tid >> 6;
        const int v = rcnt[tid];
        int incl = v;
        #pragma unroll
        for (int off = 1; off < 64; off <<= 1) {
            int t = __shfl_up(incl, off, 64);
            if (lane >= off) incl += t;
        }
        if (lane == 63) wsum[wid] = incl;
        __syncthreads();
        int woff = 0;
        #pragma unroll
        for (int w = 0; w < 4; ++w) woff += (w < wid) ? wsum[w] : 0;
        const int ex = woff + incl - v;

        cur[tid] = base + ex;
        const int r = (k << 8) + tid;
        if (r < n) row_ptr[r] = base + ex;
        if (k == nbuck - 1 && tid == 0) row_ptr[n] = next;
    } else {
        __syncthreads();
    }
    __syncthreads();

    if (fit) {
        for (int i = tid; i < cnt; i += 1024) {
            int2 p  = cache[i];
            int pos = atomicAdd(&cur[(p.x >> 17) & 255], 1);
            edges[pos] = make_int2(p.x & 0x1FFFF, p.y);
        }
    } else {
        for (int i = base + tid; i < next; i += 1024) {
            int2 p  = staging[i];
            int pos = atomicAdd(&cur[(p.x >> 17) & 255], 1);
            edges[pos] = make_int2(p.x & 0x1FFFF, p.y);
        }
    }
}

// int8-gather SpMM. One wave per row. lane = 16*g + l:
//   g = lane>>4 : edge slot; l = lane&15 : dims [8l, 8l+8) as one int2 (8 int8).
// Dequant: v_perm builds fp16(1024+q) pairs from bytes; +(-1152) centers
// to exact q-128; hfma2 accumulates with sv = s_col * (val*256) in fp16;
// descale by 1/256 on conversion to f32.
// mode 0: quantize row -> xqout int8 + scout scale.
// mode 1: out[row] = (emb + deq(x1) + deq(x2) + s) * 0.25 (fp32)
__global__ void __launch_bounds__(256)
lgcn_spmm(const int* __restrict__ row_ptr, const int2* __restrict__ edges,
          const int2* __restrict__ xq, const float* __restrict__ scin,
          int2* __restrict__ xqout, float* __restrict__ scout,
          const float2* __restrict__ emb, const int2* __restrict__ x1q,
          const float* __restrict__ sc1, float2* __restrict__ out,
          int n, int mode) {
    const int wave = blockIdx.x * 4 + (threadIdx.x >> 6);
    const int lane = threadIdx.x & 63;
    const int g    = lane >> 4;
    const int l    = lane & 15;
    if (wave >= n) return;
    const int beg = row_ptr[wave];
    const int end = row_ptr[wave + 1];

    H2 A0, A1, A2, A3;
    A0.u = 0; A1.u = 0; A2.u = 0; A3.u = 0;
    H2 BIAS; BIAS.u = 0xE480E480;  // fp16 -1152 x2

#define QFMA8(QQ, SV)                                                         \
    {                                                                         \
        H2 hv; hv.h = __float2half2_rn(SV);                                   \
        H2 p;                                                                 \
        p.u = __builtin_amdgcn_perm(0x64646464u, (unsigned)(QQ).x, 0x05010400u); \
        A0.h = __hfma2(__hadd2(p.h, BIAS.h), hv.h, A0.h);                     \
        p.u = __builtin_amdgcn_perm(0x64646464u, (unsigned)(QQ).x, 0x05030402u); \
        A1.h = __hfma2(__hadd2(p.h, BIAS.h), hv.h, A1.h);                     \
        p.u = __builtin_amdgcn_perm(0x64646464u, (unsigned)(QQ).y, 0x05010400u); \
        A2.h = __hfma2(__hadd2(p.h, BIAS.h), hv.h, A2.h);                     \
        p.u = __builtin_amdgcn_perm(0x64646464u, (unsigned)(QQ).y, 0x05030402u); \
        A3.h = __hfma2(__hadd2(p.h, BIAS.h), hv.h, A3.h);                     \
    }

    int e = beg;
    for (; e + 16 <= end; e += 16) {
        int2 d0 = edges[e + g];
        int2 d1 = edges[e + 4 + g];
        int2 d2 = edges[e + 8 + g];
        int2 d3 = edges[e + 12 + g];
        float s0 = scin[d0.x], s1 = scin[d1.x], s2 = scin[d2.x], s3 = scin[d3.x];
        int2 q0 = xq[d0.x * 16 + l];
        int2 q1 = xq[d1.x * 16 + l];
        int2 q2 = xq[d2.x * 16 + l];
        int2 q3 = xq[d3.x * 16 + l];
        QFMA8(q0, s0 * __int_as_float(d0.y));
        QFMA8(q1, s1 * __int_as_float(d1.y));
        QFMA8(q2, s2 * __int_as_float(d2.y));
        QFMA8(q3, s3 * __int_as_float(d3.y));
    }
    for (; e + 8 <= end; e += 8) {
        int2 d0 = edges[e + g];
        int2 d1 = edges[e + 4 + g];
        float s0 = scin[d0.x], s1 = scin[d1.x];
        int2 q0 = xq[d0.x * 16 + l];
        int2 q1 = xq[d1.x * 16 + l];
        QFMA8(q0, s0 * __int_as_float(d0.y));
        QFMA8(q1, s1 * __int_as_float(d1.y));
    }
    for (; e < end; e += 4) {
        const int ee = e + g;
        int2 d = (ee < end) ? edges[ee] : make_int2(0, 0);  // val=0 -> no contrib
        float s = scin[d.x];
        int2 q = xq[d.x * 16 + l];
        QFMA8(q, s * __int_as_float(d.y));
    }
#undef QFMA8

    // h2 -> f32 with 1/256 descale
    const float DS = 0.00390625f;
    float2 f0 = __half22float2(A0.h), f1 = __half22float2(A1.h);
    float2 f2 = __half22float2(A2.h), f3 = __half22float2(A3.h);
    float a0 = f0.x * DS, a1 = f0.y * DS, a2 = f1.x * DS, a3 = f1.y * DS;
    float a4 = f2.x * DS, a5 = f2.y * DS, a6 = f3.x * DS, a7 = f3.y * DS;

    // reduce across the 4 edge slots
    a0 += __shfl_xor(a0, 16); a0 += __shfl_xor(a0, 32);
    a1 += __shfl_xor(a1, 16); a1 += __shfl_xor(a1, 32);
    a2 += __shfl_xor(a2, 16); a2 += __shfl_xor(a2, 32);
    a3 += __shfl_xor(a3, 16); a3 += __shfl_xor(a3, 32);
    a4 += __shfl_xor(a4, 16); a4 += __shfl_xor(a4, 32);
    a5 += __shfl_xor(a5, 16); a5 += __shfl_xor(a5, 32);
    a6 += __shfl_xor(a6, 16); a6 += __shfl_xor(a6, 32);
    a7 += __shfl_xor(a7, 16); a7 += __shfl_xor(a7, 32);

    if (mode == 0) {
        // per-row max over the 16 dim-lanes (groups identical after reduce)
        float m = fmaxf(fmaxf(fmaxf(fabsf(a0), fabsf(a1)), fmaxf(fabsf(a2), fabsf(a3))),
                        fmaxf(fmaxf(fabsf(a4), fabsf(a5)), fmaxf(fabsf(a6), fabsf(a7))));
        m = fmaxf(m, __shfl_xor(m, 1));
        m = fmaxf(m, __shfl_xor(m, 2));
        m = fmaxf(m, __shfl_xor(m, 4));
        m = fmaxf(m, __shfl_xor(m, 8));
        const float inv = 127.0f / fmaxf(m, 1e-20f);
        int q0 = min(max((int)(a0 * inv + 128.5f), 0), 255);
        int q1 = min(max((int)(a1 * inv + 128.5f), 0), 255);
        int q2 = min(max((int)(a2 * inv + 128.5f), 0), 255);
        int q3 = min(max((int)(a3 * inv + 128.5f), 0), 255);
        int q4 = min(max((int)(a4 * inv + 128.5f), 0), 255);
        int q5 = min(max((int)(a5 * inv + 128.5f), 0), 255);
        int q6 = min(max((int)(a6 * inv + 128.5f), 0), 255);
        int q7 = min(max((int)(a7 * inv + 128.5f), 0), 255);
        if (g == 0) {
            int2 r;
            r.x = q0 | (q1 << 8) | (q2 << 16) | (q3 << 24);
            r.y = q4 | (q5 << 8) | (q6 << 16) | (q7 << 24);
            xqout[wave * 16 + l] = r;
            if (l == 0) scout[wave] = m * (1.0f / 127.0f);
        }
    } else {
        if (g == 0) {
            float4 e0 = ((const float4*)emb)[wave * 32 + l * 2 + 0];
            float4 e1 = ((const float4*)emb)[wave * 32 + l * 2 + 1];
            int2 u1 = x1q[wave * 16 + l];
            int2 u2 = xq[wave * 16 + l];
            const float s1 = sc1[wave],  o1 = -128.0f * s1;
            const float s2 = scin[wave], o2 = -128.0f * s2;
            float b0 = fmaf((float)( u1.x        & 255), s1, o1);
            float b1 = fmaf((float)((u1.x >> 8)  & 255), s1, o1);
            float b2 = fmaf((float)((u1.x >> 16) & 255), s1, o1);
            float b3 = fmaf((float)((u1.x >> 24) & 255), s1, o1);
            float b4 = fmaf((float)( u1.y        & 255), s1, o1);
            float b5 = fmaf((float)((u1.y >> 8)  & 255), s1, o1);
            float b6 = fmaf((float)((u1.y >> 16) & 255), s1, o1);
            float b7 = fmaf((float)((u1.y >> 24) & 255), s1, o1);
            float c0 = fmaf((float)( u2.x        & 255), s2, o2);
            float c1 = fmaf((float)((u2.x >> 8)  & 255), s2, o2);
            float c2 = fmaf((float)((u2.x >> 16) & 255), s2, o2);
            float c3 = fmaf((float)((u2.x >> 24) & 255), s2, o2);
            float c4 = fmaf((float)( u2.y        & 255), s2, o2);
            float c5 = fmaf((float)((u2.y >> 8)  & 255), s2, o2);
            float c6 = fmaf((float)((u2.y >> 16) & 255), s2, o2);
            float c7 = fmaf((float)((u2.y >> 24) & 255), s2, o2);
            float4 r0, r1;
            r0.x = (e0.x + b0 + c0 + a0) * 0.25f;
            r0.y = (e0.y + b1 + c1 + a1) * 0.25f;
            r0.z = (e0.z + b2 + c2 + a2) * 0.25f;
            r0.w = (e0.w + b3 + c3 + a3) * 0.25f;
            r1.x = (e1.x + b4 + c4 + a4) * 0.25f;
            r1.y = (e1.y + b5 + c5 + a5) * 0.25f;
            r1.z = (e1.z + b6 + c6 + a6) * 0.25f;
            r1.w = (e1.w + b7 + c7 + a7) * 0.25f;
            ((float4*)out)[wave * 32 + l * 2 + 0] = r0;
            ((float4*)out)[wave * 32 + l * 2 + 1] = r1;
        }
    }
}

extern "C" void kernel_launch(void* const* d_in, const int* in_sizes, int n_in,
                              void* d_out, int out_size, void* d_ws, size_t ws_size,
                              hipStream_t stream) {
    const float* emb  = (const float*)d_in[0];
    const int*   rows = (const int*)d_in[1];
    const int*   cols = (const int*)d_in[2];
    const float* vals = (const float*)d_in[3];

    const int  n_nodes = in_sizes[0] / DIM;    // 100000
    const int  nedges  = in_sizes[1];          // 2000000
    const long nd      = (long)n_nodes * DIM;  // 12.8M bytes per int8 buffer

    char* ws = (char*)d_ws;
    size_t off = 0;
    int2* bufA    = (int2*)(ws + off); off = align_up(off + (size_t)nd, 256);      // x0q then x2q
    int2* bufB    = (int2*)(ws + off); off = align_up(off + (size_t)nd, 256);      // x1q
    int2* edges   = (int2*)(ws + off); off = align_up(off + (size_t)nedges * 8, 256);
    int2* staging = (int2*)(ws + off); off = align_up(off + (size_t)nedges * 8, 256);
    float* scA    = (float*)(ws + off); off = align_up(off + (size_t)n_nodes * 4, 256);
    float* scB    = (float*)(ws + off); off = align_up(off + (size_t)n_nodes * 4, 256);
    int* row_ptr  = (int*)(ws + off);  off = align_up(off + (size_t)(n_nodes + 1) * 4, 256);
    int* ghist    = (int*)(ws + off);  off = align_up(off + (size_t)NSCAN * 4, 256);
    int* gbase    = (int*)(ws + off);  off = align_up(off + ((size_t)NSCAN + 1) * 4, 256);
    unsigned long long* tstat = (unsigned long long*)(ws + off);
    off = align_up(off + (size_t)NTILES * 8, 256);
    float2* out   = (float2*)d_out;

    const int BS = 256;
    const int nbuck   = (n_nodes + RPB - 1) / RPB;        // 391 (<= KPAD)
    const int grid_c  = (n_nodes + 15) / 16;              // conv rows, 16/block
    const int grid_s  = (n_nodes + 3) / 4;                // 4 rows per block

    // quant-conv + histogram + scan-status zero (one kernel, 1024 thr/block)
    lgcn_prep<<<PB + 1 + grid_c, 1024, 0, stream>>>((const float2*)emb, (int*)bufA,
                                                    scA, n_nodes, rows, ghist,
                                                    nedges, tstat);
    // single-kernel decoupled-lookback scan
    lgcn_scan<<<NTILES, BS, 0, stream>>>(ghist, gbase, tstat, NSCAN);
    // deterministic partition + single-pass place
    lgcn_part<<<PB, 1024, 0, stream>>>(rows, cols, vals, gbase, staging, nedges);
    lgcn_place<<<nbuck, 1024, 0, stream>>>(gbase, staging, row_ptr, edges, n_nodes, nbuck);

    // 3 SpMM layers: x1 = A x0, x2 = A x1, out = (emb + x1 + x2 + A x2)/4
    lgcn_spmm<<<grid_s, BS, 0, stream>>>(row_ptr, edges, bufA, scA, bufB, scB,
                                         nullptr, nullptr, nullptr, nullptr,
                                         n_nodes, 0);
    lgcn_spmm<<<grid_s, BS, 0, stream>>>(row_ptr, edges, bufB, scB, bufA, scA,
                                         nullptr, nullptr, nullptr, nullptr,
                                         n_nodes, 0);
    lgcn_spmm<<<grid_s, BS, 0, stream>>>(row_ptr, edges, bufA, scA, nullptr, nullptr,
                                         (const float2*)emb, bufB, scB, out,
                                         n_nodes, 1);
}